// Round 11
// baseline (223.946 us; speedup 1.0000x reference)
//
#include <hip/hip_runtime.h>

// DynamicWeightedLoss: weighted CE (CCL dynamic weights) + dice + focal.
// B=16, C=4, H=W=512. Output: 1 float.
// parent encoding after K1:  >=0: pointer toward slab root (open component)
//   -1/-2/-4: unmasked pixel of class t (enc = -(1+t), t in {0,1,3})
//   <=-8:     resolved masked pixel, component id = -8-enc  (id = root>>1;
//             roots never adjacent -> ids collision-free in [0, NPIX/2))
// K1: LDS union-find per 4096-px slab; closed components (not touching an
//     open slab boundary) finalized in K1 (counts[id]=area plain store).
// K2: inter-slab boundary unions (global CAS, open components only).
// K3: flatten+count ONLY open pixels (parent>=0).
// K4: loss partials + last-block final reduce (agent-scope release/acquire).
// ws: parent[NPIX] int | counts[NPIX/2] int | partials[2048*16] float | done

namespace {
constexpr int IMG_W = 512;
constexpr int NB    = 16;
constexpr int NC    = 4;
constexpr int HW    = 512 * 512;        // 262144
constexpr int NPIX  = NB * HW;          // 4194304
constexpr int SLAB  = 4096;             // 8 rows per K1 block
constexpr int NSLAB = NPIX / SLAB;      // 1024
constexpr int NID   = NPIX / 2;
constexpr int LOSS_BLOCKS = 2048;
constexpr int PART_STRIDE = 16;
constexpr float ALPHA  = 1.0f;
constexpr float BETA   = 0.7f;
constexpr float UPPER  = 1000.0f;
constexpr float LOWER  = 200.0f;
constexpr float W_UP   = 2.5f;
constexpr float W_LO   = 20.0f;
constexpr float SMOOTH = 1.0f;
}

// ---------- global union-find (K2/K3) ----------
__device__ __forceinline__ int ld_par(const int* parent, int i) {
    return __hip_atomic_load(&parent[i], __ATOMIC_RELAXED, __HIP_MEMORY_SCOPE_AGENT);
}

__device__ __forceinline__ int find_root_g(int* parent, int x) {
    int p = ld_par(parent, x);
    while (p != x) { x = p; p = ld_par(parent, x); }
    return x;
}

__device__ __forceinline__ void unite_g(int* parent, int a, int b) {
    int ra = find_root_g(parent, a);
    int rb = find_root_g(parent, b);
    while (ra != rb) {
        int lo = ra < rb ? ra : rb;
        int hi = ra < rb ? rb : ra;
        int old = atomicCAS(&parent[hi], hi, lo);
        if (old == hi) return;
        ra = find_root_g(parent, old);
        rb = find_root_g(parent, lo);
    }
}

// ---------- LDS union-find (K1) ----------
__device__ __forceinline__ int ld_lp(int* lp, int i) {
    return __hip_atomic_load(&lp[i], __ATOMIC_RELAXED, __HIP_MEMORY_SCOPE_WORKGROUP);
}

__device__ __forceinline__ void unite_l(int* lp, int a, int b) {
    int ra = a, rb = b;
    { int p = ld_lp(lp, ra); while (p != ra) { ra = p; p = ld_lp(lp, ra); } }
    { int p = ld_lp(lp, rb); while (p != rb) { rb = p; p = ld_lp(lp, rb); } }
    while (ra != rb) {
        int lo = ra < rb ? ra : rb;
        int hi = ra < rb ? rb : ra;
        int old = atomicCAS(&lp[hi], hi, lo);
        if (old == hi) return;
        { int p = old; while (true) { int n = ld_lp(lp, p); if (n == p) break; p = n; } ra = p; }
        { int p = lo;  while (true) { int n = ld_lp(lp, p); if (n == p) break; p = n; } rb = p; }
    }
}

__device__ __forceinline__ float wave_reduce(float v) {
    #pragma unroll
    for (int off = 32; off > 0; off >>= 1) v += __shfl_down(v, off);
    return v;
}

// K1: slab CCL in LDS, areas in LDS, closed components finalized here.
__global__ void __launch_bounds__(256)
k1_init(const int* __restrict__ tgt, int* __restrict__ parent,
        int* __restrict__ counts, int* __restrict__ done) {
    __shared__ int lp[SLAB];       // 16 KB: pointers (>=0) or class enc (<0)
    __shared__ int larea[SLAB];    // 16 KB: area per local root; bit31 = open
    const int tid = threadIdx.x, bid = blockIdx.x;
    const int base = bid * SLAB;
    const int lane = tid & 63;
    if (bid == 0 && tid == 0)
        __hip_atomic_store(done, 0, __ATOMIC_RELAXED, __HIP_MEMORY_SCOPE_AGENT);

    unsigned mk16 = 0;   // 1 bit per iter: tgt==2
    #pragma unroll
    for (int it = 0; it < 16; ++it) {
        int l = it * 256 + tid;
        int t = tgt[base + l];
        bool mk = (t == 2);
        mk16 |= (unsigned)mk << it;
        unsigned long long bal = __ballot(mk);
        int par;
        if (mk) {
            unsigned long long below = (1ull << lane) - 1ull;
            unsigned long long zb = (~bal) & below;
            int rs = (zb == 0ull) ? 0 : (64 - __clzll(zb));
            par = l - lane + rs;            // run start within 64-px segment
        } else {
            par = -(1 + t);                 // class encoding (t != 2)
        }
        lp[l] = par;
        larea[l] = 0;
    }
    __syncthreads();

    // local unions: 64-px-boundary horizontal + vertical
    #pragma unroll 1
    for (int it = 0; it < 16; ++it) {
        if (!((mk16 >> it) & 1u)) continue;
        int l = it * 256 + tid;
        if (lane == 0 && (l & (IMG_W - 1)) != 0 && ld_lp(lp, l - 1) >= 0)
            unite_l(lp, l, l - 1);
        if (it >= 2 && ((mk16 >> (it - 2)) & 1u))
            unite_l(lp, l, l - IMG_W);
    }
    __syncthreads();

    // per-root areas + open flags (component touches a mergeable boundary row)
    const bool top_open = (bid & 63) != 0;
    const bool bot_open = (bid & 63) != 63;
    #pragma unroll 1
    for (int it = 0; it < 16; ++it) {
        if (!((mk16 >> it) & 1u)) continue;
        int l = it * 256 + tid;
        int p = lp[l];
        while (true) { int n = lp[p]; if (n == p) break; p = n; }
        atomicAdd(&larea[p], 1);
        if ((it < 2 && top_open) || (it >= 14 && bot_open))
            atomicOr(&larea[p], (int)0x80000000);
    }
    __syncthreads();

    // write global parent (int4); finalize closed components
    #pragma unroll
    for (int q = 0; q < 4; ++q) {
        int l0 = (q * 256 + tid) * 4;
        int vj[4];
        #pragma unroll
        for (int j = 0; j < 4; ++j) {
            int l = l0 + j;
            int p = lp[l];
            if (p < 0) { vj[j] = p; continue; }       // unmasked class enc
            while (true) { int n = lp[p]; if (n == p) break; p = n; }
            int a = larea[p];
            if (a < 0) {                               // open component
                vj[j] = base + p;
                if (l == p) counts[(base + p) >> 1] = 0;   // zero its id slot
            } else {                                   // closed: finalize
                int id = (base + p) >> 1;
                vj[j] = -8 - id;
                if (l == p) counts[id] = a;
            }
        }
        *reinterpret_cast<int4*>(&parent[base + l0]) =
            make_int4(vj[0], vj[1], vj[2], vj[3]);
    }
}

// K2: inter-slab boundary vertical unions (open components only).
__global__ void __launch_bounds__(256)
k2_boundary(const int* __restrict__ tgt, int* parent) {
    int gid = blockIdx.x * 256 + threadIdx.x;   // NSLAB*512 threads
    int s   = gid >> 9;
    int col = gid & 511;
    if ((s & 63) == 0) return;                  // image's first row
    int px = s * SLAB + col;
    if (tgt[px] == 2 && tgt[px - IMG_W] == 2) unite_g(parent, px, px - IMG_W);
}

// K3: flatten+count OPEN pixels only (parent >= 0).
__global__ void __launch_bounds__(256)
k3_open(int* parent, int* counts) {
    int q0 = (blockIdx.x * 256 + threadIdx.x) * 4;
    int4 pv = *reinterpret_cast<const int4*>(&parent[q0]);
    int vj[4] = {pv.x, pv.y, pv.z, pv.w};
    bool any = false;
    #pragma unroll
    for (int j = 0; j < 4; ++j) {
        int v = vj[j];
        if (v < 0) continue;                    // unmasked or already final
        int id;
        while (true) {
            int nxt = ld_par(parent, v);
            if (nxt == v)   { id = v >> 1;   break; }  // true root
            if (nxt <= -8)  { id = -8 - nxt; break; }  // resolved elsewhere
            v = nxt;
        }
        vj[j] = -8 - id;
        any = true;
        atomicAdd(&counts[id], 1);
    }
    if (any)
        *reinterpret_cast<int4*>(&parent[q0]) = make_int4(vj[0], vj[1], vj[2], vj[3]);
}

// K4: loss partials + last-block final reduce. tgt not needed (class in parent).
__global__ void __launch_bounds__(256)
k4_loss(const float* __restrict__ logits, const float* __restrict__ cw,
        const int* __restrict__ parent, const int* __restrict__ counts,
        float* __restrict__ partials, int* __restrict__ done,
        float* __restrict__ out) {
    const int bid = blockIdx.x, tid = threadIdx.x;
    const int b    = bid >> 7;
    const int slab = bid & 127;
    const float* Lb = logits + (size_t)b * NC * HW;
    const int*   Pb = parent + (size_t)b * HW;
    float cw0 = cw[0], cw1 = cw[1], cw2 = cw[2], cw3 = cw[3];

    float a_wce = 0.f, a_foc = 0.f;
    float a_ps[4] = {0.f, 0.f, 0.f, 0.f};
    float a_in[4] = {0.f, 0.f, 0.f, 0.f};
    float a_ct[4] = {0.f, 0.f, 0.f, 0.f};

    #pragma unroll
    for (int it = 0; it < 2; ++it) {
        int p = slab * 2048 + (it * 256 + tid) * 4;
        int4 e4 = *reinterpret_cast<const int4*>(&Pb[p]);
        int ej[4] = {e4.x, e4.y, e4.z, e4.w};
        float4 x0 = *reinterpret_cast<const float4*>(&Lb[p]);
        float4 x1 = *reinterpret_cast<const float4*>(&Lb[p + HW]);
        float4 x2 = *reinterpret_cast<const float4*>(&Lb[p + 2 * HW]);
        float4 x3 = *reinterpret_cast<const float4*>(&Lb[p + 3 * HW]);
        float c0[4] = {x0.x, x0.y, x0.z, x0.w};
        float c1[4] = {x1.x, x1.y, x1.z, x1.w};
        float c2[4] = {x2.x, x2.y, x2.z, x2.w};
        float c3[4] = {x3.x, x3.y, x3.z, x3.w};
        #pragma unroll
        for (int j = 0; j < 4; ++j) {
            float v0 = c0[j], v1 = c1[j], v2 = c2[j], v3 = c3[j];
            int   e  = ej[j];
            int   t  = (e >= -4) ? (-1 - e) : 2;   // class from encoding
            float m  = fmaxf(fmaxf(v0, v1), fmaxf(v2, v3));
            float e0 = __expf(v0 - m), e1 = __expf(v1 - m);
            float e2 = __expf(v2 - m), e3 = __expf(v3 - m);
            float S  = e0 + e1 + e2 + e3;
            float invS = __frcp_rn(S);
            float xt = (t == 0) ? v0 : (t == 1) ? v1 : (t == 2) ? v2 : v3;
            float wt = (t == 0) ? cw0 : (t == 1) ? cw1 : (t == 2) ? cw2 : cw3;
            float nll = __logf(S) + m - xt;
            float ce  = wt * nll;
            float pt  = __expf(-ce);
            float omp = 1.0f - pt;
            float focal_i = ALPHA * omp * omp * ce;
            float dyn = 1.0f;
            if (e <= -8) {
                float area = (float)counts[-8 - e];
                float interp = W_UP + (W_LO - W_UP) * (UPPER - area) * (1.0f / (UPPER - LOWER));
                dyn = (area > UPPER) ? W_UP : (area < LOWER) ? W_LO : interp;
            }
            float pr0 = e0 * invS, pr1 = e1 * invS, pr2 = e2 * invS, pr3 = e3 * invS;
            float prt = (t == 0) ? pr0 : (t == 1) ? pr1 : (t == 2) ? pr2 : pr3;
            a_wce += ce * dyn;
            a_foc += focal_i;
            a_ps[0] += pr0; a_ps[1] += pr1; a_ps[2] += pr2; a_ps[3] += pr3;
            a_in[t] += prt;
            a_ct[t] += 1.0f;
        }
    }

    float vals[14];
    vals[0] = a_wce; vals[1] = a_foc;
    vals[2] = a_ps[0]; vals[3] = a_ps[1]; vals[4] = a_ps[2]; vals[5] = a_ps[3];
    vals[6] = a_in[0]; vals[7] = a_in[1]; vals[8] = a_in[2]; vals[9] = a_in[3];
    vals[10] = a_ct[0]; vals[11] = a_ct[1]; vals[12] = a_ct[2]; vals[13] = a_ct[3];

    __shared__ float red[14][4];
    int lane = tid & 63, wv = tid >> 6;
    #pragma unroll
    for (int i = 0; i < 14; ++i) {
        float v = wave_reduce(vals[i]);
        if (lane == 0) red[i][wv] = v;
    }
    __syncthreads();
    if (tid < 14) {
        float s = red[tid][0] + red[tid][1] + red[tid][2] + red[tid][3];
        __hip_atomic_store(&partials[bid * PART_STRIDE + tid], s,
                           __ATOMIC_RELEASE, __HIP_MEMORY_SCOPE_AGENT);
    }
    __syncthreads();

    __shared__ int lastv;
    if (tid == 0) {
        int prev = __hip_atomic_fetch_add(done, 1, __ATOMIC_ACQ_REL,
                                          __HIP_MEMORY_SCOPE_AGENT);
        lastv = (prev == LOSS_BLOCKS - 1) ? 1 : 0;
    }
    __syncthreads();
    if (!lastv) return;

    // final reduce (last block): 4 waves x 4 images each
    __shared__ double sw[4], sf[4], sd[4];
    double dw = 0.0, df = 0.0, dd = 0.0;
    for (int img = wv; img < NB; img += 4) {
        float v[14];
        #pragma unroll
        for (int i = 0; i < 14; ++i) {
            float a = __hip_atomic_load(&partials[(img * 128 + lane) * PART_STRIDE + i],
                                        __ATOMIC_RELAXED, __HIP_MEMORY_SCOPE_AGENT);
            float c = __hip_atomic_load(&partials[(img * 128 + 64 + lane) * PART_STRIDE + i],
                                        __ATOMIC_RELAXED, __HIP_MEMORY_SCOPE_AGENT);
            v[i] = a + c;
        }
        #pragma unroll
        for (int i = 0; i < 14; ++i) v[i] = wave_reduce(v[i]);
        if (lane == 0) {
            dw += v[0]; df += v[1];
            #pragma unroll
            for (int c = 0; c < 4; ++c) {
                double inter = v[6 + c], psum = v[2 + c], cnt = v[10 + c];
                dd += (2.0 * inter + (double)SMOOTH) / (psum + cnt + (double)SMOOTH);
            }
        }
    }
    if (lane == 0) { sw[wv] = dw; sf[wv] = df; sd[wv] = dd; }
    __syncthreads();
    if (tid == 0) {
        double wce = 0.0, foc = 0.0, dice = 0.0;
        #pragma unroll
        for (int i = 0; i < 4; ++i) { wce += sw[i]; foc += sf[i]; dice += sd[i]; }
        double dice_mean = dice / (double)(NB * NC);
        out[0] = (float)((double)BETA * (wce / (double)NPIX)
                         + (1.0 - (double)BETA) * (1.0 - dice_mean)
                         + (foc / (double)NPIX));
    }
}

extern "C" void kernel_launch(void* const* d_in, const int* in_sizes, int n_in,
                              void* d_out, int out_size, void* d_ws, size_t ws_size,
                              hipStream_t stream) {
    const float* logits = (const float*)d_in[0];
    const float* cw     = (const float*)d_in[1];
    const int*   tgt    = (const int*)d_in[2];
    float*       out    = (float*)d_out;
    char*        ws     = (char*)d_ws;
    int*   parent   = (int*)ws;
    int*   counts   = (int*)(ws + (size_t)NPIX * 4);
    float* partials = (float*)(ws + (size_t)NPIX * 4 + (size_t)NID * 4);
    int*   done     = (int*)(ws + (size_t)NPIX * 4 + (size_t)NID * 4
                             + (size_t)LOSS_BLOCKS * PART_STRIDE * 4);

    hipLaunchKernelGGL(k1_init, dim3(NSLAB), dim3(256), 0, stream,
                       tgt, parent, counts, done);
    hipLaunchKernelGGL(k2_boundary, dim3(NSLAB * IMG_W / 256), dim3(256), 0, stream,
                       tgt, parent);
    hipLaunchKernelGGL(k3_open, dim3(NPIX / 1024), dim3(256), 0, stream,
                       parent, counts);
    hipLaunchKernelGGL(k4_loss, dim3(LOSS_BLOCKS), dim3(256), 0, stream,
                       logits, cw, parent, counts, partials, done, out);
}

// Round 17
// 169.961 us; speedup vs baseline: 1.3176x; 1.3176x over previous
//
#include <hip/hip_runtime.h>

// DynamicWeightedLoss: weighted CE (CCL dynamic weights) + dice + focal.
// B=16, C=4, H=W=512. Output: 1 float.
// parent encoding after K1:  >=0: pointer toward slab root (open component)
//   -1/-2/-4: unmasked pixel of class t (enc = -(1+t), t in {0,1,3})
//   <=-8:     resolved masked pixel, component id = -8-enc  (id = root>>1;
//             roots never adjacent -> ids collision-free in [0, NPIX/2))
// K1: LDS union-find per 4096-px slab; closed components finalized in K1.
// K2: inter-slab boundary unions (global CAS, open components only).
// K3: flatten+count ONLY open pixels (parent>=0).
// K4: loss partials (plain stores, no atomics). K5: final reduce (1 block).
// ws: parent[NPIX] int | counts[NPIX/2] int | partials[2048*16] float

namespace {
constexpr int IMG_W = 512;
constexpr int NB    = 16;
constexpr int NC    = 4;
constexpr int HW    = 512 * 512;        // 262144
constexpr int NPIX  = NB * HW;          // 4194304
constexpr int SLAB  = 4096;             // 8 rows per K1 block
constexpr int NSLAB = NPIX / SLAB;      // 1024
constexpr int NID   = NPIX / 2;
constexpr int LOSS_BLOCKS = 2048;
constexpr int PART_STRIDE = 16;
constexpr float ALPHA  = 1.0f;
constexpr float BETA   = 0.7f;
constexpr float UPPER  = 1000.0f;
constexpr float LOWER  = 200.0f;
constexpr float W_UP   = 2.5f;
constexpr float W_LO   = 20.0f;
constexpr float SMOOTH = 1.0f;
}

// ---------- global union-find (K2/K3) ----------
__device__ __forceinline__ int ld_par(const int* parent, int i) {
    return __hip_atomic_load(&parent[i], __ATOMIC_RELAXED, __HIP_MEMORY_SCOPE_AGENT);
}

__device__ __forceinline__ int find_root_g(int* parent, int x) {
    int p = ld_par(parent, x);
    while (p != x) { x = p; p = ld_par(parent, x); }
    return x;
}

__device__ __forceinline__ void unite_g(int* parent, int a, int b) {
    int ra = find_root_g(parent, a);
    int rb = find_root_g(parent, b);
    while (ra != rb) {
        int lo = ra < rb ? ra : rb;
        int hi = ra < rb ? rb : ra;
        int old = atomicCAS(&parent[hi], hi, lo);
        if (old == hi) return;
        ra = find_root_g(parent, old);
        rb = find_root_g(parent, lo);
    }
}

// ---------- LDS union-find (K1) ----------
__device__ __forceinline__ int ld_lp(int* lp, int i) {
    return __hip_atomic_load(&lp[i], __ATOMIC_RELAXED, __HIP_MEMORY_SCOPE_WORKGROUP);
}

__device__ __forceinline__ void unite_l(int* lp, int a, int b) {
    int ra = a, rb = b;
    { int p = ld_lp(lp, ra); while (p != ra) { ra = p; p = ld_lp(lp, ra); } }
    { int p = ld_lp(lp, rb); while (p != rb) { rb = p; p = ld_lp(lp, rb); } }
    while (ra != rb) {
        int lo = ra < rb ? ra : rb;
        int hi = ra < rb ? rb : ra;
        int old = atomicCAS(&lp[hi], hi, lo);
        if (old == hi) return;
        { int p = old; while (true) { int n = ld_lp(lp, p); if (n == p) break; p = n; } ra = p; }
        { int p = lo;  while (true) { int n = ld_lp(lp, p); if (n == p) break; p = n; } rb = p; }
    }
}

__device__ __forceinline__ float wave_reduce(float v) {
    #pragma unroll
    for (int off = 32; off > 0; off >>= 1) v += __shfl_down(v, off);
    return v;
}

// K1: slab CCL in LDS, areas in LDS, closed components finalized here.
__global__ void __launch_bounds__(256)
k1_init(const int* __restrict__ tgt, int* __restrict__ parent,
        int* __restrict__ counts) {
    __shared__ int lp[SLAB];       // 16 KB: pointers (>=0) or class enc (<0)
    __shared__ int larea[SLAB];    // 16 KB: area per local root; bit31 = open
    const int tid = threadIdx.x, bid = blockIdx.x;
    const int base = bid * SLAB;
    const int lane = tid & 63;

    unsigned mk16 = 0;   // 1 bit per iter: tgt==2
    #pragma unroll
    for (int it = 0; it < 16; ++it) {
        int l = it * 256 + tid;
        int t = tgt[base + l];
        bool mk = (t == 2);
        mk16 |= (unsigned)mk << it;
        unsigned long long bal = __ballot(mk);
        int par;
        if (mk) {
            unsigned long long below = (1ull << lane) - 1ull;
            unsigned long long zb = (~bal) & below;
            int rs = (zb == 0ull) ? 0 : (64 - __clzll(zb));
            par = l - lane + rs;            // run start within 64-px segment
        } else {
            par = -(1 + t);                 // class encoding (t != 2)
        }
        lp[l] = par;
        larea[l] = 0;
    }
    __syncthreads();

    // local unions: 64-px-boundary horizontal + vertical
    #pragma unroll 1
    for (int it = 0; it < 16; ++it) {
        if (!((mk16 >> it) & 1u)) continue;
        int l = it * 256 + tid;
        if (lane == 0 && (l & (IMG_W - 1)) != 0 && ld_lp(lp, l - 1) >= 0)
            unite_l(lp, l, l - 1);
        if (it >= 2 && ((mk16 >> (it - 2)) & 1u))
            unite_l(lp, l, l - IMG_W);
    }
    __syncthreads();

    // per-root areas + open flags (component touches a mergeable boundary row)
    const bool top_open = (bid & 63) != 0;
    const bool bot_open = (bid & 63) != 63;
    #pragma unroll 1
    for (int it = 0; it < 16; ++it) {
        if (!((mk16 >> it) & 1u)) continue;
        int l = it * 256 + tid;
        int p = lp[l];
        while (true) { int n = lp[p]; if (n == p) break; p = n; }
        atomicAdd(&larea[p], 1);
        if ((it < 2 && top_open) || (it >= 14 && bot_open))
            atomicOr(&larea[p], (int)0x80000000);
    }
    __syncthreads();

    // write global parent (int4); finalize closed components
    #pragma unroll
    for (int q = 0; q < 4; ++q) {
        int l0 = (q * 256 + tid) * 4;
        int vj[4];
        #pragma unroll
        for (int j = 0; j < 4; ++j) {
            int l = l0 + j;
            int p = lp[l];
            if (p < 0) { vj[j] = p; continue; }       // unmasked class enc
            while (true) { int n = lp[p]; if (n == p) break; p = n; }
            int a = larea[p];
            if (a < 0) {                               // open component
                vj[j] = base + p;
                if (l == p) counts[(base + p) >> 1] = 0;   // zero its id slot
            } else {                                   // closed: finalize
                int id = (base + p) >> 1;
                vj[j] = -8 - id;
                if (l == p) counts[id] = a;
            }
        }
        *reinterpret_cast<int4*>(&parent[base + l0]) =
            make_int4(vj[0], vj[1], vj[2], vj[3]);
    }
}

// K2: inter-slab boundary vertical unions (open components only).
__global__ void __launch_bounds__(256)
k2_boundary(const int* __restrict__ tgt, int* parent) {
    int gid = blockIdx.x * 256 + threadIdx.x;   // NSLAB*512 threads
    int s   = gid >> 9;
    int col = gid & 511;
    if ((s & 63) == 0) return;                  // image's first row
    int px = s * SLAB + col;
    if (tgt[px] == 2 && tgt[px - IMG_W] == 2) unite_g(parent, px, px - IMG_W);
}

// K3: flatten+count OPEN pixels only (parent >= 0).
__global__ void __launch_bounds__(256)
k3_open(int* parent, int* counts) {
    int q0 = (blockIdx.x * 256 + threadIdx.x) * 4;
    int4 pv = *reinterpret_cast<const int4*>(&parent[q0]);
    int vj[4] = {pv.x, pv.y, pv.z, pv.w};
    bool any = false;
    #pragma unroll
    for (int j = 0; j < 4; ++j) {
        int v = vj[j];
        if (v < 0) continue;                    // unmasked or already final
        int id;
        while (true) {
            int nxt = ld_par(parent, v);
            if (nxt == v)   { id = v >> 1;   break; }  // true root
            if (nxt <= -8)  { id = -8 - nxt; break; }  // resolved elsewhere
            v = nxt;
        }
        vj[j] = -8 - id;
        any = true;
        atomicAdd(&counts[id], 1);
    }
    if (any)
        *reinterpret_cast<int4*>(&parent[q0]) = make_int4(vj[0], vj[1], vj[2], vj[3]);
}

// K4: loss partials, plain stores, no atomics. Class comes from parent enc.
__global__ void __launch_bounds__(256)
k4_loss(const float* __restrict__ logits, const float* __restrict__ cw,
        const int* __restrict__ parent, const int* __restrict__ counts,
        float* __restrict__ partials) {
    const int bid = blockIdx.x, tid = threadIdx.x;
    const int b    = bid >> 7;
    const int slab = bid & 127;
    const float* Lb = logits + (size_t)b * NC * HW;
    const int*   Pb = parent + (size_t)b * HW;
    float cw0 = cw[0], cw1 = cw[1], cw2 = cw[2], cw3 = cw[3];

    float a_wce = 0.f, a_foc = 0.f;
    float a_ps[4] = {0.f, 0.f, 0.f, 0.f};
    float a_in[4] = {0.f, 0.f, 0.f, 0.f};
    float a_ct[4] = {0.f, 0.f, 0.f, 0.f};

    #pragma unroll
    for (int it = 0; it < 2; ++it) {
        int p = slab * 2048 + (it * 256 + tid) * 4;
        int4 e4 = *reinterpret_cast<const int4*>(&Pb[p]);
        int ej[4] = {e4.x, e4.y, e4.z, e4.w};
        float4 x0 = *reinterpret_cast<const float4*>(&Lb[p]);
        float4 x1 = *reinterpret_cast<const float4*>(&Lb[p + HW]);
        float4 x2 = *reinterpret_cast<const float4*>(&Lb[p + 2 * HW]);
        float4 x3 = *reinterpret_cast<const float4*>(&Lb[p + 3 * HW]);
        float c0[4] = {x0.x, x0.y, x0.z, x0.w};
        float c1[4] = {x1.x, x1.y, x1.z, x1.w};
        float c2[4] = {x2.x, x2.y, x2.z, x2.w};
        float c3[4] = {x3.x, x3.y, x3.z, x3.w};
        #pragma unroll
        for (int j = 0; j < 4; ++j) {
            float v0 = c0[j], v1 = c1[j], v2 = c2[j], v3 = c3[j];
            int   e  = ej[j];
            int   t  = (e >= -4) ? (-1 - e) : 2;   // class from encoding
            float m  = fmaxf(fmaxf(v0, v1), fmaxf(v2, v3));
            float e0 = __expf(v0 - m), e1 = __expf(v1 - m);
            float e2 = __expf(v2 - m), e3 = __expf(v3 - m);
            float S  = e0 + e1 + e2 + e3;
            float invS = __frcp_rn(S);
            float xt = (t == 0) ? v0 : (t == 1) ? v1 : (t == 2) ? v2 : v3;
            float wt = (t == 0) ? cw0 : (t == 1) ? cw1 : (t == 2) ? cw2 : cw3;
            float nll = __logf(S) + m - xt;
            float ce  = wt * nll;
            float pt  = __expf(-ce);
            float omp = 1.0f - pt;
            float focal_i = ALPHA * omp * omp * ce;
            float dyn = 1.0f;
            if (e <= -8) {
                float area = (float)counts[-8 - e];
                float interp = W_UP + (W_LO - W_UP) * (UPPER - area) * (1.0f / (UPPER - LOWER));
                dyn = (area > UPPER) ? W_UP : (area < LOWER) ? W_LO : interp;
            }
            float pr0 = e0 * invS, pr1 = e1 * invS, pr2 = e2 * invS, pr3 = e3 * invS;
            float prt = (t == 0) ? pr0 : (t == 1) ? pr1 : (t == 2) ? pr2 : pr3;
            a_wce += ce * dyn;
            a_foc += focal_i;
            a_ps[0] += pr0; a_ps[1] += pr1; a_ps[2] += pr2; a_ps[3] += pr3;
            a_in[t] += prt;
            a_ct[t] += 1.0f;
        }
    }

    float vals[14];
    vals[0] = a_wce; vals[1] = a_foc;
    vals[2] = a_ps[0]; vals[3] = a_ps[1]; vals[4] = a_ps[2]; vals[5] = a_ps[3];
    vals[6] = a_in[0]; vals[7] = a_in[1]; vals[8] = a_in[2]; vals[9] = a_in[3];
    vals[10] = a_ct[0]; vals[11] = a_ct[1]; vals[12] = a_ct[2]; vals[13] = a_ct[3];

    __shared__ float red[14][4];
    int lane = tid & 63, wv = tid >> 6;
    #pragma unroll
    for (int i = 0; i < 14; ++i) {
        float v = wave_reduce(vals[i]);
        if (lane == 0) red[i][wv] = v;
    }
    __syncthreads();
    if (tid < 14)
        partials[bid * PART_STRIDE + tid] =
            red[tid][0] + red[tid][1] + red[tid][2] + red[tid][3];
}

// K5: 1 block, 1024 threads = 16 waves; wave w reduces image w's 128 partials.
__global__ void __launch_bounds__(1024)
k5_final(const float* __restrict__ partials, float* __restrict__ out) {
    int tid = threadIdx.x, lane = tid & 63, w = tid >> 6;
    const float* r0 = &partials[(w * 128 + lane) * PART_STRIDE];
    const float* r1 = &partials[(w * 128 + 64 + lane) * PART_STRIDE];
    float v[14];
    #pragma unroll
    for (int i = 0; i < 14; ++i) v[i] = r0[i] + r1[i];
    #pragma unroll
    for (int i = 0; i < 14; ++i) v[i] = wave_reduce(v[i]);

    __shared__ double s_wce[16], s_foc[16], s_dice[16];
    if (lane == 0) {
        double dsum = 0.0;
        #pragma unroll
        for (int c = 0; c < 4; ++c) {
            double inter = v[6 + c], psum = v[2 + c], cnt = v[10 + c];
            dsum += (2.0 * inter + (double)SMOOTH) / (psum + cnt + (double)SMOOTH);
        }
        s_wce[w] = v[0]; s_foc[w] = v[1]; s_dice[w] = dsum;
    }
    __syncthreads();
    if (tid == 0) {
        double wce = 0.0, foc = 0.0, dice = 0.0;
        for (int i = 0; i < 16; ++i) { wce += s_wce[i]; foc += s_foc[i]; dice += s_dice[i]; }
        double dice_mean = dice / (double)(NB * NC);
        out[0] = (float)((double)BETA * (wce / (double)NPIX)
                         + (1.0 - (double)BETA) * (1.0 - dice_mean)
                         + (foc / (double)NPIX));
    }
}

extern "C" void kernel_launch(void* const* d_in, const int* in_sizes, int n_in,
                              void* d_out, int out_size, void* d_ws, size_t ws_size,
                              hipStream_t stream) {
    const float* logits = (const float*)d_in[0];
    const float* cw     = (const float*)d_in[1];
    const int*   tgt    = (const int*)d_in[2];
    float*       out    = (float*)d_out;
    char*        ws     = (char*)d_ws;
    int*   parent   = (int*)ws;
    int*   counts   = (int*)(ws + (size_t)NPIX * 4);
    float* partials = (float*)(ws + (size_t)NPIX * 4 + (size_t)NID * 4);

    hipLaunchKernelGGL(k1_init, dim3(NSLAB), dim3(256), 0, stream,
                       tgt, parent, counts);
    hipLaunchKernelGGL(k2_boundary, dim3(NSLAB * IMG_W / 256), dim3(256), 0, stream,
                       tgt, parent);
    hipLaunchKernelGGL(k3_open, dim3(NPIX / 1024), dim3(256), 0, stream,
                       parent, counts);
    hipLaunchKernelGGL(k4_loss, dim3(LOSS_BLOCKS), dim3(256), 0, stream,
                       logits, cw, parent, counts, partials);
    hipLaunchKernelGGL(k5_final, dim3(1), dim3(1024), 0, stream, partials, out);
}